// Round 1
// baseline (640.002 us; speedup 1.0000x reference)
//
#include <hip/hip_runtime.h>

// ---------------------------------------------------------------------------
// LIIF-style MLP render on MI355X.
//  B=4, C=64, H=W=128, Q=65536, dims 68->256->256->256->256->3, 4 shifts.
//  Total rows = B*Q*4 = 1,048,576.  Main kernel: 4096 blocks x 512 thr,
//  256 rows/block, fp16 MFMA 16x16x32, activations resident in LDS (128KB,
//  XOR-swizzled), weights pre-packed to B-fragment layout and staged per
//  K=32 panel (16KB).
// ---------------------------------------------------------------------------

typedef _Float16 half8 __attribute__((ext_vector_type(8)));
typedef float f32x4 __attribute__((ext_vector_type(4)));

#define NB       4
#define NC       64
#define NH       128
#define NW       128
#define NQ       65536
#define HID      256
#define ROWS     256          // rows per block (query-shift pairs)
#define THREADS  512

// LDS layout (dynamic): A activations [256 rows][256 k] fp16, 512 B/row
#define A_BYTES   131072
#define BPAN_OFF  131072      // 16 KiB weight panel (aliased by pred buffer)
#define AREA_OFF  147456      // 256 x f32 areas
#define SMEM_BYTES 148480

static __device__ __forceinline__ unsigned short f2h(float f) {
    union { _Float16 h; unsigned short u; } v;
    v.h = (_Float16)f;   // v_cvt_f16_f32, RNE
    return v.u;
}

// swizzle: XOR 16B-slot index with row&7 (keeps 16B alignment, bijective)
#define SWZ(row, byte) ((byte) ^ (((row) & 7) << 4))

// ---------------------------------------------------------------------------
// feat [B][C][H][W] f32  ->  featT [B][H][W][C] fp16  (LDS tile transpose)
// ---------------------------------------------------------------------------
__global__ void transpose_feat(const float* __restrict__ feat,
                               unsigned short* __restrict__ featT) {
    __shared__ float tile[64][65];
    const int bi  = blockIdx.x;          // B*H*2 = 1024 blocks
    const int b   = bi >> 8;
    const int rem = bi & 255;
    const int y   = rem >> 1;
    const int xc  = (rem & 1) << 6;
    const int tid = threadIdx.x;

    {
        const int x  = tid & 63;
        const int cg = tid >> 6;          // 0..3
#pragma unroll
        for (int i = 0; i < 16; ++i) {
            int c = cg * 16 + i;
            tile[c][x] = feat[(((b << 6) + c) << 14) + (y << 7) + xc + x];
        }
    }
    __syncthreads();
    {
        const int c  = tid & 63;
        const int xg = tid >> 6;
#pragma unroll
        for (int i = 0; i < 16; ++i) {
            int xx = xg * 16 + i;
            featT[(size_t)((((b << 7) + y) << 7) + xc + xx) * 64 + c] =
                f2h(tile[c][xx]);
        }
    }
}

// ---------------------------------------------------------------------------
// Pack weight [K][N] f32 -> fragment layout fp16:
//   dst[((ks*nct + ct)*64 + lane)*8 + j] = W[ks*32 + (lane>>4)*8 + j][ct*16 + (lane&15)]
// zero-padded outside K,N.
// ---------------------------------------------------------------------------
__global__ void pack_w(const float* __restrict__ src,
                       unsigned short* __restrict__ dst,
                       int K, int N, int ksteps, int nct) {
    int tid = blockIdx.x * 256 + threadIdx.x;
    int total = ksteps * nct * 512;
    if (tid >= total) return;
    int j    = tid & 7;
    int lane = (tid >> 3) & 63;
    int f    = tid >> 9;
    int ct   = f % nct;
    int ks   = f / nct;
    int k = ks * 32 + ((lane >> 4) << 3) + j;
    int n = ct * 16 + (lane & 15);
    float v = (k < K && n < N) ? src[k * N + n] : 0.0f;
    dst[tid] = f2h(v);
}

// ---------------------------------------------------------------------------
// Main fused kernel
// ---------------------------------------------------------------------------
__global__ __launch_bounds__(512, 2) void mlp_main(
    const unsigned short* __restrict__ featT,
    const float* __restrict__ sgrid,
    const float* __restrict__ scell,
    const unsigned short* __restrict__ wp0, const unsigned short* __restrict__ wp1,
    const unsigned short* __restrict__ wp2, const unsigned short* __restrict__ wp3,
    const unsigned short* __restrict__ wp4,
    const float* __restrict__ bp0, const float* __restrict__ bp1,
    const float* __restrict__ bp2, const float* __restrict__ bp3,
    const float* __restrict__ bp4,
    float* __restrict__ out) {

    extern __shared__ char lds[];
    char*  A     = lds;                          // 256 x 512B fp16 activations
    char*  Bp    = lds + BPAN_OFF;               // 16KB weight panel
    float* areas = (float*)(lds + AREA_OFF);     // 256 f32
    float* predl = (float*)(lds + BPAN_OFF);     // alias: 256 x 4 f32 preds

    const int tid  = threadIdx.x;
    const int lane = tid & 63;
    const int wv   = tid >> 6;     // wave 0..7
    const int wm   = wv >> 2;      // row half (0..1)
    const int wn   = wv & 3;       // col quarter (0..3)

    // ---------------- phase 0: build MLP inputs into A ----------------
    {
        const int row  = tid >> 1;
        const int half = tid & 1;
        const int grow = blockIdx.x * ROWS + row;
        const int qq   = grow >> 2;        // global query index (b*Q+q)
        const int s    = grow & 3;         // shift: 0:(-,-) 1:(-,+) 2:(+,-) 3:(+,+)
        const int b    = qq >> 16;

        const float g0 = sgrid[qq * 2 + 0];
        const float g1 = sgrid[qq * 2 + 1];
        const float c0 = scell[qq * 2 + 0];
        const float c1 = scell[qq * 2 + 1];

        const float rs = (s & 2) ? 1.0f : -1.0f;
        const float cs = (s & 1) ? 1.0f : -1.0f;
        const float dh = 0.0078125f;                   // 1/128
        const float LO = (float)(-1.0 + 1e-6);
        const float HI = (float)( 1.0 - 1e-6);

        // exact same fp32 op order as reference
        float gy = fminf(fmaxf(g0 + rs * dh, LO), HI);
        float gx = fminf(fmaxf(g1 + cs * dh, LO), HI);
        float ty = ((gy + 1.0f) * 128.0f - 1.0f) * 0.5f;
        float tx = ((gx + 1.0f) * 128.0f - 1.0f) * 0.5f;
        int iy = (int)rintf(ty); iy = min(max(iy, 0), 127);
        int ix = (int)rintf(tx); ix = min(max(ix, 0), 127);

        float py = -1.0f + (float)(2 * iy + 1) * 0.0078125f;
        float px = -1.0f + (float)(2 * ix + 1) * 0.0078125f;
        float rel_y = (g0 - py) * 128.0f;
        float rel_x = (g1 - px) * 128.0f;
        float qcy = c0 * 128.0f;
        float qcx = c1 * 128.0f;

        if (half == 0) areas[row] = fabsf(rel_y * rel_x) + 1e-9f;

        // gather 32 channels (64B) of fp16 features
        const unsigned short* src =
            featT + (size_t)((((b << 7) + iy) << 7) + ix) * 64 + (half << 5);
        uint4 v0 = *(const uint4*)(src + 0);
        uint4 v1 = *(const uint4*)(src + 8);
        uint4 v2 = *(const uint4*)(src + 16);
        uint4 v3 = *(const uint4*)(src + 24);

        char* arow = A + row * 512;
        const int kb0 = half << 6;     // byte offset of k = half*32
        *(uint4*)(arow + SWZ(row, kb0 +  0)) = v0;
        *(uint4*)(arow + SWZ(row, kb0 + 16)) = v1;
        *(uint4*)(arow + SWZ(row, kb0 + 32)) = v2;
        *(uint4*)(arow + SWZ(row, kb0 + 48)) = v3;

        if (half) {    // k = 64..95 : rel_y, rel_x, qcy, qcx, zeros
            uint4 t;
            t.x = (unsigned)f2h(rel_y) | ((unsigned)f2h(rel_x) << 16);
            t.y = (unsigned)f2h(qcy)   | ((unsigned)f2h(qcx)   << 16);
            t.z = 0; t.w = 0;
            uint4 z = {0, 0, 0, 0};
            *(uint4*)(arow + SWZ(row, 128)) = t;
            *(uint4*)(arow + SWZ(row, 144)) = z;
            *(uint4*)(arow + SWZ(row, 160)) = z;
            *(uint4*)(arow + SWZ(row, 176)) = z;
        }
    }
    __syncthreads();

    // ---------------- layers 0..3 (K-panel loop, relu) ----------------
    f32x4 acc[8][4];
    for (int L = 0; L < 4; ++L) {
        const unsigned short* wsel = (L == 0) ? wp0 : (L == 1) ? wp1 : (L == 2) ? wp2 : wp3;
        const float*          bsel = (L == 0) ? bp0 : (L == 1) ? bp1 : (L == 2) ? bp2 : bp3;
        const int NP = (L == 0) ? 3 : 8;

#pragma unroll
        for (int rf = 0; rf < 8; ++rf)
#pragma unroll
            for (int cf = 0; cf < 4; ++cf)
                acc[rf][cf] = (f32x4){0.f, 0.f, 0.f, 0.f};

        const uint4* wsg = (const uint4*)wsel;
        uint4 st0 = wsg[tid * 2];
        uint4 st1 = wsg[tid * 2 + 1];

        for (int kp = 0; kp < NP; ++kp) {
            __syncthreads();                       // prev panel reads done
            ((uint4*)Bp)[tid * 2]     = st0;
            ((uint4*)Bp)[tid * 2 + 1] = st1;
            if (kp + 1 < NP) {
                st0 = wsg[(kp + 1) * 1024 + tid * 2];
                st1 = wsg[(kp + 1) * 1024 + tid * 2 + 1];
            }
            __syncthreads();                       // panel visible

            half8 af[8], bf[4];
            const int kbyte = (kp << 6) + ((lane >> 4) << 4);
            const int xorv  = (lane & 7) << 4;
#pragma unroll
            for (int rf = 0; rf < 8; ++rf) {
                int row = wm * 128 + rf * 16 + (lane & 15);
                af[rf] = *(const half8*)(A + row * 512 + (kbyte ^ xorv));
            }
#pragma unroll
            for (int cf = 0; cf < 4; ++cf)
                bf[cf] = *(const half8*)(Bp + (wn * 4 + cf) * 1024 + lane * 16);
#pragma unroll
            for (int rf = 0; rf < 8; ++rf)
#pragma unroll
                for (int cf = 0; cf < 4; ++cf)
                    acc[rf][cf] = __builtin_amdgcn_mfma_f32_16x16x32_f16(
                        af[rf], bf[cf], acc[rf][cf], 0, 0, 0);
        }
        __syncthreads();   // all A reads of this layer done

        // bias + relu + write activations back (fp16, swizzled)
        float bias[4];
#pragma unroll
        for (int cf = 0; cf < 4; ++cf)
            bias[cf] = bsel[wn * 64 + cf * 16 + (lane & 15)];

#pragma unroll
        for (int rf = 0; rf < 8; ++rf) {
            const int rbase = wm * 128 + rf * 16 + ((lane >> 4) << 2);
#pragma unroll
            for (int q = 0; q < 4; ++q) {
                const int row = rbase + q;
                char* arow = A + row * 512;
                const int rx = (row & 7) << 4;
#pragma unroll
                for (int cf = 0; cf < 4; ++cf) {
                    float v = acc[rf][cf][q] + bias[cf];
                    v = fmaxf(v, 0.0f);
                    int kb = (wn * 64 + cf * 16 + (lane & 15)) * 2;
                    *(unsigned short*)(arow + (kb ^ rx)) = f2h(v);
                }
            }
        }
        __syncthreads();
    }

    // ---------------- layer 4 (256 -> 3, N padded to 16) ----------------
    {
        ((uint4*)Bp)[tid] = ((const uint4*)wp4)[tid];   // 8KB stage
        __syncthreads();

        f32x4 a4[2];
        a4[0] = (f32x4){0.f, 0.f, 0.f, 0.f};
        a4[1] = (f32x4){0.f, 0.f, 0.f, 0.f};
        const int xorv = (lane & 7) << 4;
#pragma unroll
        for (int kp = 0; kp < 8; ++kp) {
            const int kbyte = (kp << 6) + ((lane >> 4) << 4);
            half8 b = *(const half8*)(Bp + kp * 1024 + lane * 16);
#pragma unroll
            for (int rr = 0; rr < 2; ++rr) {
                int row = wv * 32 + rr * 16 + (lane & 15);
                half8 a = *(const half8*)(A + row * 512 + (kbyte ^ xorv));
                a4[rr] = __builtin_amdgcn_mfma_f32_16x16x32_f16(a, b, a4[rr], 0, 0, 0);
            }
        }
        __syncthreads();   // done reading Bp (predl aliases it)

        const int col = lane & 15;
        const float b4v = (col < 3) ? bp4[col] : 0.0f;
#pragma unroll
        for (int rr = 0; rr < 2; ++rr)
#pragma unroll
            for (int q = 0; q < 4; ++q) {
                int row = wv * 32 + rr * 16 + ((lane >> 4) << 2) + q;
                if (col < 3) predl[row * 4 + col] = a4[rr][q] + b4v;
            }
        __syncthreads();

        // combine 4 shifts with diagonally swapped areas
        if (tid < 192) {
            int qloc = tid / 3;
            int c    = tid - qloc * 3;
            int r0   = qloc * 4;
            float a0 = areas[r0 + 0], a1 = areas[r0 + 1];
            float a2 = areas[r0 + 2], a3 = areas[r0 + 3];
            float total = ((a0 + a1) + a2) + a3;
            float ret = predl[(r0 + 0) * 4 + c] * (a3 / total);
            ret      += predl[(r0 + 1) * 4 + c] * (a2 / total);
            ret      += predl[(r0 + 2) * 4 + c] * (a1 / total);
            ret      += predl[(r0 + 3) * 4 + c] * (a0 / total);
            int qq0 = blockIdx.x * 64 + qloc;
            out[qq0 * 3 + c] = ret;
        }
    }
}

// ---------------------------------------------------------------------------
extern "C" void kernel_launch(void* const* d_in, const int* in_sizes, int n_in,
                              void* d_out, int out_size, void* d_ws, size_t ws_size,
                              hipStream_t stream) {
    const float* feat  = (const float*)d_in[0];
    const float* sgrid = (const float*)d_in[1];
    const float* scell = (const float*)d_in[2];
    const float* w0 = (const float*)d_in[3];
    const float* b0 = (const float*)d_in[4];
    const float* w1 = (const float*)d_in[5];
    const float* b1 = (const float*)d_in[6];
    const float* w2 = (const float*)d_in[7];
    const float* b2 = (const float*)d_in[8];
    const float* w3 = (const float*)d_in[9];
    const float* b3 = (const float*)d_in[10];
    const float* w4 = (const float*)d_in[11];
    const float* b4 = (const float*)d_in[12];

    char* ws = (char*)d_ws;
    // ws layout (bytes):
    //   featT fp16 [4][128][128][64] : 8,388,608
    //   wp0 (3 ksteps x 16 ct)       :    49,152
    //   wp1..wp3 (8 x 16)            :   131,072 each
    //   wp4 (8 x 1)                  :     8,192
    unsigned short* featT = (unsigned short*)ws;
    unsigned short* wp0 = (unsigned short*)(ws + 8388608);
    unsigned short* wp1 = (unsigned short*)(ws + 8388608 + 49152);
    unsigned short* wp2 = (unsigned short*)(ws + 8388608 + 49152 + 131072);
    unsigned short* wp3 = (unsigned short*)(ws + 8388608 + 49152 + 2 * 131072);
    unsigned short* wp4 = (unsigned short*)(ws + 8388608 + 49152 + 3 * 131072);

    transpose_feat<<<1024, 256, 0, stream>>>(feat, featT);
    pack_w<<<96,  256, 0, stream>>>(w0, wp0,  68, 256, 3, 16);
    pack_w<<<256, 256, 0, stream>>>(w1, wp1, 256, 256, 8, 16);
    pack_w<<<256, 256, 0, stream>>>(w2, wp2, 256, 256, 8, 16);
    pack_w<<<256, 256, 0, stream>>>(w3, wp3, 256, 256, 8, 16);
    pack_w<<<16,  256, 0, stream>>>(w4, wp4, 256, 3, 8, 1);

    hipFuncSetAttribute(reinterpret_cast<const void*>(mlp_main),
                        hipFuncAttributeMaxDynamicSharedMemorySize, SMEM_BYTES);
    mlp_main<<<4096, THREADS, SMEM_BYTES, stream>>>(
        featT, sgrid, scell, wp0, wp1, wp2, wp3, wp4,
        b0, b1, b2, b3, b4, (float*)d_out);
}

// Round 4
// 610.653 us; speedup vs baseline: 1.0481x; 1.0481x over previous
//
#include <hip/hip_runtime.h>

// ---------------------------------------------------------------------------
// LIIF-style MLP render on MI355X — R4 (bisect).
//  EXACT R1 geometry & numerics (512 thr / 8 waves / 256 rows / acc[8][4],
//  scalar b16 writeback, epilogue bias). ONLY change vs R1: B-fragments are
//  read directly from global (no LDS staging, no per-panel barriers).
// ---------------------------------------------------------------------------

typedef _Float16 half8 __attribute__((ext_vector_type(8)));
typedef float f32x4 __attribute__((ext_vector_type(4)));

#define ROWS     256          // rows per block (query-shift pairs)
#define THREADS  512

#define A_BYTES    131072     // 256 rows x 512 B (256 k x fp16)
#define AREA_OFF   131072     // 256 x f32
#define PRED_OFF   132096     // 256 x 4 x f32
#define SMEM_BYTES 136192

static __device__ __forceinline__ unsigned short f2h(float f) {
    union { _Float16 h; unsigned short u; } v;
    v.h = (_Float16)f;   // v_cvt_f16_f32, RNE
    return v.u;
}

// swizzle: XOR 16B-slot index with row&7 (keeps 16B alignment, bijective)
#define SWZ(row, byte) ((byte) ^ (((row) & 7) << 4))

// ---------------------------------------------------------------------------
// feat [B][C][H][W] f32  ->  featT [B][H][W][C] fp16  (LDS tile transpose)
// ---------------------------------------------------------------------------
__global__ void transpose_feat(const float* __restrict__ feat,
                               unsigned short* __restrict__ featT) {
    __shared__ float tile[64][65];
    const int bi  = blockIdx.x;          // B*H*2 = 1024 blocks
    const int b   = bi >> 8;
    const int rem = bi & 255;
    const int y   = rem >> 1;
    const int xc  = (rem & 1) << 6;
    const int tid = threadIdx.x;

    {
        const int x  = tid & 63;
        const int cg = tid >> 6;          // 0..3
#pragma unroll
        for (int i = 0; i < 16; ++i) {
            int c = cg * 16 + i;
            tile[c][x] = feat[(((b << 6) + c) << 14) + (y << 7) + xc + x];
        }
    }
    __syncthreads();
    {
        const int c  = tid & 63;
        const int xg = tid >> 6;
#pragma unroll
        for (int i = 0; i < 16; ++i) {
            int xx = xg * 16 + i;
            featT[(size_t)((((b << 7) + y) << 7) + xc + xx) * 64 + c] =
                f2h(tile[c][xx]);
        }
    }
}

// ---------------------------------------------------------------------------
// Pack weight [K][N] f32 -> fragment layout fp16 (R1-verified):
//   dst[((ks*nct + ct)*64 + lane)*8 + j] = W[ks*32 + (lane>>4)*8 + j][ct*16 + (lane&15)]
// zero-padded outside K,N.
// ---------------------------------------------------------------------------
__global__ void pack_w(const float* __restrict__ src,
                       unsigned short* __restrict__ dst,
                       int K, int N, int ksteps, int nct) {
    int tid = blockIdx.x * 256 + threadIdx.x;
    int total = ksteps * nct * 512;
    if (tid >= total) return;
    int j    = tid & 7;
    int lane = (tid >> 3) & 63;
    int f    = tid >> 9;
    int ct   = f % nct;
    int ks   = f / nct;
    int k = ks * 32 + ((lane >> 4) << 3) + j;
    int n = ct * 16 + (lane & 15);
    float v = (k < K && n < N) ? src[k * N + n] : 0.0f;
    dst[tid] = f2h(v);
}

// ---------------------------------------------------------------------------
// Main fused kernel
// ---------------------------------------------------------------------------
__global__ __launch_bounds__(512, 2) void mlp_main(
    const unsigned short* __restrict__ featT,
    const float* __restrict__ sgrid,
    const float* __restrict__ scell,
    const unsigned short* __restrict__ wp0, const unsigned short* __restrict__ wp1,
    const unsigned short* __restrict__ wp2, const unsigned short* __restrict__ wp3,
    const unsigned short* __restrict__ wp4,
    const float* __restrict__ bp0, const float* __restrict__ bp1,
    const float* __restrict__ bp2, const float* __restrict__ bp3,
    const float* __restrict__ bp4,
    float* __restrict__ out) {

    extern __shared__ char lds[];
    char*  A     = lds;                          // 256 x 512B fp16 activations
    float* areas = (float*)(lds + AREA_OFF);     // 256 f32
    float* predl = (float*)(lds + PRED_OFF);     // 256 x 4 f32

    const int tid  = threadIdx.x;
    const int lane = tid & 63;
    const int wv   = tid >> 6;     // wave 0..7
    const int wm   = wv >> 2;      // row half (0..1)
    const int wn   = wv & 3;       // col quarter (0..3)

    // ---------------- phase 0: build MLP inputs into A ----------------
    {
        const int row  = tid >> 1;
        const int half = tid & 1;
        const int grow = blockIdx.x * ROWS + row;
        const int qq   = grow >> 2;        // global query index (b*Q+q)
        const int s    = grow & 3;         // shift: 0:(-,-) 1:(-,+) 2:(+,-) 3:(+,+)
        const int b    = qq >> 16;

        const float g0 = sgrid[qq * 2 + 0];
        const float g1 = sgrid[qq * 2 + 1];
        const float c0 = scell[qq * 2 + 0];
        const float c1 = scell[qq * 2 + 1];

        const float rs = (s & 2) ? 1.0f : -1.0f;
        const float cs = (s & 1) ? 1.0f : -1.0f;
        const float dh = 0.0078125f;                   // 1/128
        const float LO = (float)(-1.0 + 1e-6);
        const float HI = (float)( 1.0 - 1e-6);

        // exact same fp32 op order as reference
        float gy = fminf(fmaxf(g0 + rs * dh, LO), HI);
        float gx = fminf(fmaxf(g1 + cs * dh, LO), HI);
        float ty = ((gy + 1.0f) * 128.0f - 1.0f) * 0.5f;
        float tx = ((gx + 1.0f) * 128.0f - 1.0f) * 0.5f;
        int iy = (int)rintf(ty); iy = min(max(iy, 0), 127);
        int ix = (int)rintf(tx); ix = min(max(ix, 0), 127);

        float py = -1.0f + (float)(2 * iy + 1) * 0.0078125f;
        float px = -1.0f + (float)(2 * ix + 1) * 0.0078125f;
        float rel_y = (g0 - py) * 128.0f;
        float rel_x = (g1 - px) * 128.0f;
        float qcy = c0 * 128.0f;
        float qcx = c1 * 128.0f;

        if (half == 0) areas[row] = fabsf(rel_y * rel_x) + 1e-9f;

        // gather 32 channels (64B) of fp16 features
        const unsigned short* src =
            featT + (size_t)((((b << 7) + iy) << 7) + ix) * 64 + (half << 5);
        uint4 v0 = *(const uint4*)(src + 0);
        uint4 v1 = *(const uint4*)(src + 8);
        uint4 v2 = *(const uint4*)(src + 16);
        uint4 v3 = *(const uint4*)(src + 24);

        char* arow = A + row * 512;
        const int kb0 = half << 6;     // byte offset of k = half*32
        *(uint4*)(arow + SWZ(row, kb0 +  0)) = v0;
        *(uint4*)(arow + SWZ(row, kb0 + 16)) = v1;
        *(uint4*)(arow + SWZ(row, kb0 + 32)) = v2;
        *(uint4*)(arow + SWZ(row, kb0 + 48)) = v3;

        if (half) {    // k = 64..95 : rel_y, rel_x, qcy, qcx, zeros
            uint4 t;
            t.x = (unsigned)f2h(rel_y) | ((unsigned)f2h(rel_x) << 16);
            t.y = (unsigned)f2h(qcy)   | ((unsigned)f2h(qcx)   << 16);
            t.z = 0; t.w = 0;
            uint4 z = {0, 0, 0, 0};
            *(uint4*)(arow + SWZ(row, 128)) = t;
            *(uint4*)(arow + SWZ(row, 144)) = z;
            *(uint4*)(arow + SWZ(row, 160)) = z;
            *(uint4*)(arow + SWZ(row, 176)) = z;
        }
    }
    __syncthreads();

    // ---------------- layers 0..3 (K-panel loop, relu) ----------------
    f32x4 acc[8][4];
    for (int L = 0; L < 4; ++L) {
        const unsigned short* wsel = (L == 0) ? wp0 : (L == 1) ? wp1 : (L == 2) ? wp2 : wp3;
        const float*          bsel = (L == 0) ? bp0 : (L == 1) ? bp1 : (L == 2) ? bp2 : bp3;
        const int NP = (L == 0) ? 3 : 8;

#pragma unroll
        for (int rf = 0; rf < 8; ++rf)
#pragma unroll
            for (int cf = 0; cf < 4; ++cf)
                acc[rf][cf] = (f32x4){0.f, 0.f, 0.f, 0.f};

        for (int kp = 0; kp < NP; ++kp) {
            half8 af[8], bf[4];
            const int kbyte = (kp << 6) + ((lane >> 4) << 4);
            const int xorv  = (lane & 7) << 4;
#pragma unroll
            for (int rf = 0; rf < 8; ++rf) {
                int row = wm * 128 + rf * 16 + (lane & 15);
                af[rf] = *(const half8*)(A + row * 512 + (kbyte ^ xorv));
            }
#pragma unroll
            for (int cf = 0; cf < 4; ++cf)
                bf[cf] = *(const half8*)(wsel + (size_t)((kp * 16 + wn * 4 + cf) * 64 + lane) * 8);
#pragma unroll
            for (int rf = 0; rf < 8; ++rf)
#pragma unroll
                for (int cf = 0; cf < 4; ++cf)
                    acc[rf][cf] = __builtin_amdgcn_mfma_f32_16x16x32_f16(
                        af[rf], bf[cf], acc[rf][cf], 0, 0, 0);
        }
        __syncthreads();   // all A reads of this layer done

        // bias + relu + write activations back (fp16, swizzled)
        float bias[4];
#pragma unroll
        for (int cf = 0; cf < 4; ++cf)
            bias[cf] = bsel[wn * 64 + cf * 16 + (lane & 15)];

#pragma unroll
        for (int rf = 0; rf < 8; ++rf) {
            const int rbase = wm * 128 + rf * 16 + ((lane >> 4) << 2);
#pragma unroll
            for (int q = 0; q < 4; ++q) {
                const int row = rbase + q;
                char* arow = A + row * 512;
                const int rx = (row & 7) << 4;
#pragma unroll
                for (int cf = 0; cf < 4; ++cf) {
                    float v = acc[rf][cf][q] + bias[cf];
                    v = fmaxf(v, 0.0f);
                    int kb = (wn * 64 + cf * 16 + (lane & 15)) * 2;
                    *(unsigned short*)(arow + (kb ^ rx)) = f2h(v);
                }
            }
        }
        __syncthreads();
    }

    // ---------------- layer 4 (256 -> 3, N padded to 16) ----------------
    {
        f32x4 a4[2];
        a4[0] = (f32x4){0.f, 0.f, 0.f, 0.f};
        a4[1] = (f32x4){0.f, 0.f, 0.f, 0.f};
        const int xorv = (lane & 7) << 4;
#pragma unroll
        for (int kp = 0; kp < 8; ++kp) {
            const int kbyte = (kp << 6) + ((lane >> 4) << 4);
            half8 b = *(const half8*)(wp4 + (size_t)((kp * 64) + lane) * 8);
#pragma unroll
            for (int rr = 0; rr < 2; ++rr) {
                int row = wv * 32 + rr * 16 + (lane & 15);
                half8 a = *(const half8*)(A + row * 512 + (kbyte ^ xorv));
                a4[rr] = __builtin_amdgcn_mfma_f32_16x16x32_f16(a, b, a4[rr], 0, 0, 0);
            }
        }
        __syncthreads();

        const int col = lane & 15;
        const float b4v = (col < 3) ? bp4[col] : 0.0f;
#pragma unroll
        for (int rr = 0; rr < 2; ++rr)
#pragma unroll
            for (int q = 0; q < 4; ++q) {
                int row = wv * 32 + rr * 16 + ((lane >> 4) << 2) + q;
                if (col < 3) predl[row * 4 + col] = a4[rr][q] + b4v;
            }
        __syncthreads();

        // combine 4 shifts with diagonally swapped areas
        if (tid < 192) {
            int qloc = tid / 3;
            int c    = tid - qloc * 3;
            int r0   = qloc * 4;
            float a0 = areas[r0 + 0], a1 = areas[r0 + 1];
            float a2 = areas[r0 + 2], a3 = areas[r0 + 3];
            float total = ((a0 + a1) + a2) + a3;
            float ret = predl[(r0 + 0) * 4 + c] * (a3 / total);
            ret      += predl[(r0 + 1) * 4 + c] * (a2 / total);
            ret      += predl[(r0 + 2) * 4 + c] * (a1 / total);
            ret      += predl[(r0 + 3) * 4 + c] * (a0 / total);
            int qq0 = blockIdx.x * 64 + qloc;
            out[qq0 * 3 + c] = ret;
        }
    }
}

// ---------------------------------------------------------------------------
extern "C" void kernel_launch(void* const* d_in, const int* in_sizes, int n_in,
                              void* d_out, int out_size, void* d_ws, size_t ws_size,
                              hipStream_t stream) {
    const float* feat  = (const float*)d_in[0];
    const float* sgrid = (const float*)d_in[1];
    const float* scell = (const float*)d_in[2];
    const float* w0 = (const float*)d_in[3];
    const float* b0 = (const float*)d_in[4];
    const float* w1 = (const float*)d_in[5];
    const float* b1 = (const float*)d_in[6];
    const float* w2 = (const float*)d_in[7];
    const float* b2 = (const float*)d_in[8];
    const float* w3 = (const float*)d_in[9];
    const float* b3 = (const float*)d_in[10];
    const float* w4 = (const float*)d_in[11];
    const float* b4 = (const float*)d_in[12];

    char* ws = (char*)d_ws;
    unsigned short* featT = (unsigned short*)ws;
    unsigned short* wp0 = (unsigned short*)(ws + 8388608);
    unsigned short* wp1 = (unsigned short*)(ws + 8388608 + 49152);
    unsigned short* wp2 = (unsigned short*)(ws + 8388608 + 49152 + 131072);
    unsigned short* wp3 = (unsigned short*)(ws + 8388608 + 49152 + 2 * 131072);
    unsigned short* wp4 = (unsigned short*)(ws + 8388608 + 49152 + 3 * 131072);

    transpose_feat<<<1024, 256, 0, stream>>>(feat, featT);
    pack_w<<<96,  256, 0, stream>>>(w0, wp0,  68, 256, 3, 16);
    pack_w<<<256, 256, 0, stream>>>(w1, wp1, 256, 256, 8, 16);
    pack_w<<<256, 256, 0, stream>>>(w2, wp2, 256, 256, 8, 16);
    pack_w<<<256, 256, 0, stream>>>(w3, wp3, 256, 256, 8, 16);
    pack_w<<<16,  256, 0, stream>>>(w4, wp4, 256, 3, 8, 1);

    hipFuncSetAttribute(reinterpret_cast<const void*>(mlp_main),
                        hipFuncAttributeMaxDynamicSharedMemorySize, SMEM_BYTES);
    mlp_main<<<4096, THREADS, SMEM_BYTES, stream>>>(
        featT, sgrid, scell, wp0, wp1, wp2, wp3, wp4,
        b0, b1, b2, b3, b4, (float*)d_out);
}